// Round 7
// baseline (237.842 us; speedup 1.0000x reference)
//
#include <hip/hip_runtime.h>
#include <hip/hip_bf16.h>

#define Sx 256
#define Dx 300
#define Mx 1024
#define CC 5.0f

// workspace layout (float-index offsets into d_ws)
#define OFF_REP     0
#define OFF_DEP     307200
#define OFF_HEAD    614400
#define OFF_ATTN    921600
#define OFF_WTFCP   1228800   // uint [150 kp][300 n]  bf16x2-packed Wfc^T
#define OFF_WT12P   1280000   // uint [150 kp][600 n]  cols 0-299 W1^T, 300-599 W2^T
#define OFF_WTF12P  1380000   // uint [300 kp][300 n]  kp 0-149 Wf1^T, 150-299 Wf2^T
#define OFF_BIAS    1480000   // fp32: bfc@+0, b1@+304, bf@+608

__device__ __forceinline__ float bf2f(unsigned short u) {
    union { unsigned int i; float f; } v; v.i = ((unsigned int)u) << 16; return v.f;
}
__device__ __forceinline__ float lo16f(unsigned int v) {
    union { unsigned int i; float f; } u; u.i = v << 16; return u.f;
}
__device__ __forceinline__ float hi16f(unsigned int v) {
    union { unsigned int i; float f; } u; u.i = v & 0xFFFF0000u; return u.f;
}
__device__ __forceinline__ unsigned short f2bf(float x) {   // RNE; exact for bf16 round-trip
    union { float f; unsigned int i; } u; u.f = x;
    unsigned int r = u.i + 0x7FFFu + ((u.i >> 16) & 1u);
    return (unsigned short)(r >> 16);
}
__device__ __forceinline__ int detect_bf16(const void* w) {
    const unsigned short* u = (const unsigned short*)w;
    int ok = 1;
    #pragma unroll
    for (int t = 0; t < 64; ++t) { float v = bf2f(u[t]); ok &= (fabsf(v) < 1.0f) ? 1 : 0; }
    return ok;
}
__device__ __forceinline__ float ldf(const void* p, int idx, int isbf) {
    return isbf ? bf2f(((const unsigned short*)p)[idx]) : ((const float*)p)[idx];
}

// ---------------------------------------------------------------------------
// k_prep: transpose + bf16x2-pack the 5 weight matrices; biases fp32.
// 501 blocks x 256 thr. Tiles 32x32, 10x10 per matrix.
// ---------------------------------------------------------------------------
__global__ __launch_bounds__(256) void k_prep(
        const void* __restrict__ Wfc, const void* __restrict__ W1,
        const void* __restrict__ W2,  const void* __restrict__ Wf1,
        const void* __restrict__ Wf2, const void* __restrict__ bfc,
        const void* __restrict__ b1,  const void* __restrict__ bfv,
        float* __restrict__ ws) {
    __shared__ float tile[32][33];
    __shared__ int s_isbf;
    if (threadIdx.x == 0) s_isbf = detect_bf16(Wfc);
    __syncthreads();
    const int isbf = s_isbf;
    const int bid = blockIdx.x;
    if (bid == 500) {
        for (int idx = threadIdx.x; idx < 912; idx += 256) {
            int wb = idx / 304, o = idx - wb * 304;
            const void* src = (wb == 0) ? bfc : (wb == 1 ? b1 : bfv);
            ws[OFF_BIAS + idx] = (o < Dx) ? ldf(src, o, isbf) : 0.0f;
        }
        return;
    }
    const int job = bid / 100, t = bid % 100;
    const int tg = t / 10, tk = t % 10;
    const void* src; unsigned int* dst; int N, colOff, kpOff;
    unsigned int* wsu = (unsigned int*)ws;
    switch (job) {
        case 0:  src = Wfc; dst = wsu + OFF_WTFCP;  N = 300; colOff = 0;   kpOff = 0;   break;
        case 1:  src = W1;  dst = wsu + OFF_WT12P;  N = 600; colOff = 0;   kpOff = 0;   break;
        case 2:  src = W2;  dst = wsu + OFF_WT12P;  N = 600; colOff = 300; kpOff = 0;   break;
        case 3:  src = Wf1; dst = wsu + OFF_WTF12P; N = 300; colOff = 0;   kpOff = 0;   break;
        default: src = Wf2; dst = wsu + OFF_WTF12P; N = 300; colOff = 0;   kpOff = 150; break;
    }
    const int tx = threadIdx.x & 31, ty = threadIdx.x >> 5;
    #pragma unroll
    for (int r = 0; r < 4; ++r) {
        int g = tg * 32 + ty + r * 8, k = tk * 32 + tx;
        if (g < Dx && k < Dx) tile[ty + r * 8][tx] = ldf(src, g * Dx + k, isbf);
    }
    __syncthreads();
    // pack: dst[(tk*16 + kp_l + kpOff)*N + colOff + g] = bf16(tile[g][2kp_l]) | bf16(tile[g][2kp_l+1])<<16
    const int gl = threadIdx.x & 31;
    const int kpl_base = (threadIdx.x >> 5);   // 0..7
    #pragma unroll
    for (int r = 0; r < 2; ++r) {
        int kpl = kpl_base + r * 8;            // 0..15
        int g = tg * 32 + gl;
        int k0 = tk * 32 + 2 * kpl;
        if (g < Dx && k0 + 1 < Dx) {
            unsigned int pk = (unsigned int)f2bf(tile[gl][2 * kpl])
                            | ((unsigned int)f2bf(tile[gl][2 * kpl + 1]) << 16);
            dst[(tk * 16 + kpl + kpOff) * N + colOff + g] = pk;
        }
    }
}

// ---------------------------------------------------------------------------
// k_mm1: rep = elu(X @ Wfc^T + bfc).  grid 320 = 64 mt x 5 nt, 256 thr
// (64 n-lanes x 4 k-groups). m_tile=16. W bf16x2; X wave-uniform loads.
// ---------------------------------------------------------------------------
__global__ __launch_bounds__(256) void k_mm1(
        const void* __restrict__ Xv, const void* __restrict__ Wdet,
        const float* __restrict__ ws_ro, float* __restrict__ rep) {
    __shared__ float red[3][64][17];
    __shared__ int s_isbf;
    const int tid = threadIdx.x;
    if (tid == 0) s_isbf = detect_bf16(Wdet);
    __syncthreads();
    const int isbf = s_isbf;
    const int lane = tid & 63, kg = tid >> 6;
    const int mt = blockIdx.x / 5, nt = blockIdx.x - mt * 5;
    const int m0 = mt * 16;
    const int n = nt * 64 + lane;
    const int nc = (n < 300) ? n : 299;
    const int kp0 = (kg == 0) ? 0 : (kg == 1) ? 38 : (kg == 2) ? 76 : 113;
    const int kp1 = (kg == 0) ? 38 : (kg == 1) ? 76 : (kg == 2) ? 113 : 150;
    const unsigned int* wp = (const unsigned int*)ws_ro + OFF_WTFCP + nc;
    float acc[16];
    #pragma unroll
    for (int m = 0; m < 16; ++m) acc[m] = 0.f;
    if (isbf) {
        const unsigned int* xu = (const unsigned int*)Xv + m0 * 150;
        #pragma unroll 2
        for (int kp = kp0; kp < kp1; ++kp) {
            unsigned int wv = wp[kp * 300];
            float w0 = lo16f(wv), w1 = hi16f(wv);
            #pragma unroll
            for (int m = 0; m < 16; ++m) {
                unsigned int xv = xu[m * 150 + kp];
                acc[m] = fmaf(lo16f(xv), w0, fmaf(hi16f(xv), w1, acc[m]));
            }
        }
    } else {
        const float2* xf = (const float2*)((const float*)Xv + m0 * 300);
        #pragma unroll 2
        for (int kp = kp0; kp < kp1; ++kp) {
            unsigned int wv = wp[kp * 300];
            float w0 = lo16f(wv), w1 = hi16f(wv);
            #pragma unroll
            for (int m = 0; m < 16; ++m) {
                float2 xv = xf[m * 150 + kp];
                acc[m] = fmaf(xv.x, w0, fmaf(xv.y, w1, acc[m]));
            }
        }
    }
    if (kg > 0) {
        #pragma unroll
        for (int m = 0; m < 16; ++m) red[kg - 1][lane][m] = acc[m];
    }
    __syncthreads();
    if (kg == 0 && n < 300) {
        float bb = ws_ro[OFF_BIAS + n];
        #pragma unroll
        for (int m = 0; m < 16; ++m) {
            float v = acc[m] + red[0][lane][m] + red[1][lane][m] + red[2][lane][m] + bb;
            v = v > 0.f ? v : (__expf(v) - 1.f);
            rep[(m0 + m) * 300 + n] = v;
        }
    }
}

// ---------------------------------------------------------------------------
// k_mm2: dep = rep@W1^T + b1 ; head = rep@W2^T.  grid 640 = 64 mt x 10 nt.
// ---------------------------------------------------------------------------
__global__ __launch_bounds__(256) void k_mm2(
        const float* __restrict__ ws_ro, float* __restrict__ ws) {
    __shared__ float red[3][64][17];
    const int tid = threadIdx.x;
    const int lane = tid & 63, kg = tid >> 6;
    const int mt = blockIdx.x / 10, nt = blockIdx.x - mt * 10;
    const int m0 = mt * 16;
    const int n = nt * 64 + lane;
    const int nc = (n < 600) ? n : 599;
    const int kp0 = (kg == 0) ? 0 : (kg == 1) ? 38 : (kg == 2) ? 76 : 113;
    const int kp1 = (kg == 0) ? 38 : (kg == 1) ? 76 : (kg == 2) ? 113 : 150;
    const unsigned int* wp = (const unsigned int*)ws_ro + OFF_WT12P + nc;
    const float2* xf = (const float2*)(ws_ro + OFF_REP + m0 * 300);
    float acc[16];
    #pragma unroll
    for (int m = 0; m < 16; ++m) acc[m] = 0.f;
    #pragma unroll 2
    for (int kp = kp0; kp < kp1; ++kp) {
        unsigned int wv = wp[kp * 600];
        float w0 = lo16f(wv), w1 = hi16f(wv);
        #pragma unroll
        for (int m = 0; m < 16; ++m) {
            float2 xv = xf[m * 150 + kp];
            acc[m] = fmaf(xv.x, w0, fmaf(xv.y, w1, acc[m]));
        }
    }
    if (kg > 0) {
        #pragma unroll
        for (int m = 0; m < 16; ++m) red[kg - 1][lane][m] = acc[m];
    }
    __syncthreads();
    if (kg == 0 && n < 600) {
        float bb = (n < 300) ? ws_ro[OFF_BIAS + 304 + n] : 0.0f;
        float* dst = (n < 300) ? (ws + OFF_DEP + n) : (ws + OFF_HEAD + (n - 300));
        #pragma unroll
        for (int m = 0; m < 16; ++m) {
            float v = acc[m] + red[0][lane][m] + red[1][lane][m] + red[2][lane][m] + bb;
            dst[(m0 + m) * 300] = v;
        }
    }
}

// ---------------------------------------------------------------------------
// k_attn: single pass, branchless, fixed shift m=C (proven round 4).
// grid 512, 320 thr; 2-i tiles long/short interleaved.
// ---------------------------------------------------------------------------
__global__ __launch_bounds__(320) void k_attn(
        const float* __restrict__ ws_ro, const int* __restrict__ mask,
        float* __restrict__ attn) {
    const float* dep  = ws_ro + OFF_DEP;
    const float* head = ws_ro + OFF_HEAD;
    const float* rep  = ws_ro + OFF_REP;
    __shared__ float mkf[256];
    const int blk = blockIdx.x;
    const int b = blk >> 7;
    const int tile = blk & 127;
    const int u = tile >> 1;
    const int i0 = (tile & 1) ? (254 - 2 * u) : (2 * u);
    const int tid = threadIdx.x;
    if (tid < 256) mkf[tid] = (float)mask[b * 256 + tid];
    __syncthreads();
    const int d = tid;
    if (d >= Dx) return;
    const int base = b * 256;

    const float hv0 = head[(base + i0) * Dx + d];
    const float hv1 = head[(base + i0 + 1) * Dx + d];
    const float pw0 = __expf(0.4f * hv0);
    const float pw1 = __expf(0.4f * hv1);

    float s0 = 0.f, r0 = 0.f, s1 = 0.f, r1 = 0.f;
    {
        const int j = i0 + 1;
        float dv = dep[(base + j) * Dx + d];
        float rv = rep[(base + j) * Dx + d];
        float mk = mkf[j];
        float ex = __expf(0.4f * dv);
        float u0 = fmaf(ex, pw0, 1.0f);
        float e0 = __expf(-10.0f * __builtin_amdgcn_rcpf(u0));
        float em0 = e0 * mk;
        s0 += em0; r0 = fmaf(em0, rv, r0);
    }
    const float* dp = dep + base * Dx + d;
    const float* rp = rep + base * Dx + d;
    #pragma unroll 4
    for (int j = i0 + 2; j < 256; ++j) {
        float dv = dp[j * Dx];
        float rv = rp[j * Dx];
        float mk = mkf[j];
        float ex = __expf(0.4f * dv);
        float u0 = fmaf(ex, pw0, 1.0f);
        float u1 = fmaf(ex, pw1, 1.0f);
        float e0 = __expf(-10.0f * __builtin_amdgcn_rcpf(u0));
        float e1 = __expf(-10.0f * __builtin_amdgcn_rcpf(u1));
        float em0 = e0 * mk;
        float em1 = e1 * mk;
        s0 += em0; r0 = fmaf(em0, rv, r0);
        s1 += em1; r1 = fmaf(em1, rv, r1);
    }
    const float den0 = s0 + (s0 == 0.f ? 1.f : 0.f) + 1e-20f;
    const float den1 = s1 + (s1 == 0.f ? 1.f : 0.f) + 1e-20f;
    attn[(base + i0) * Dx + d]     = r0 / den0;
    attn[(base + i0 + 1) * Dx + d] = r1 / den1;
}

// ---------------------------------------------------------------------------
// k_mm3: gate = sigmoid([rep|attn] @ [Wf1|Wf2]^T + bf); blend; mask; store.
// grid 320 = 64 mt x 5 nt; K=600 (300 pairs, 4 groups of 75).
// ---------------------------------------------------------------------------
__global__ __launch_bounds__(256) void k_mm3(
        const float* __restrict__ ws_ro, const void* __restrict__ Wdet,
        const int* __restrict__ mask, void* __restrict__ outv) {
    __shared__ float red[3][64][17];
    __shared__ int s_isbf;
    const int tid = threadIdx.x;
    if (tid == 0) s_isbf = detect_bf16(Wdet);
    __syncthreads();
    const int isbf = s_isbf;
    const int lane = tid & 63, kg = tid >> 6;
    const int mt = blockIdx.x / 5, nt = blockIdx.x - mt * 5;
    const int m0 = mt * 16;
    const int n = nt * 64 + lane;
    const int nc = (n < 300) ? n : 299;
    const int kp0 = kg * 75, kp1 = kp0 + 75;
    const int kpo = (kg < 2) ? 0 : 150;
    const unsigned int* wp = (const unsigned int*)ws_ro + OFF_WTF12P + nc;
    const float* xbase = ws_ro + ((kg < 2) ? OFF_REP : OFF_ATTN) + m0 * 300;
    const float2* xf = (const float2*)xbase;
    float acc[16];
    #pragma unroll
    for (int m = 0; m < 16; ++m) acc[m] = 0.f;
    #pragma unroll 2
    for (int kp = kp0; kp < kp1; ++kp) {
        unsigned int wv = wp[kp * 300];
        float w0 = lo16f(wv), w1 = hi16f(wv);
        const int kx = kp - kpo;
        #pragma unroll
        for (int m = 0; m < 16; ++m) {
            float2 xv = xf[m * 150 + kx];
            acc[m] = fmaf(xv.x, w0, fmaf(xv.y, w1, acc[m]));
        }
    }
    if (kg > 0) {
        #pragma unroll
        for (int m = 0; m < 16; ++m) red[kg - 1][lane][m] = acc[m];
    }
    __syncthreads();
    if (kg == 0 && n < 300) {
        float bb = ws_ro[OFF_BIAS + 608 + n];
        const float* rep  = ws_ro + OFF_REP;
        const float* attn = ws_ro + OFF_ATTN;
        #pragma unroll
        for (int m = 0; m < 16; ++m) {
            float gp = acc[m] + red[0][lane][m] + red[1][lane][m] + red[2][lane][m] + bb;
            float gate = 1.0f / (1.0f + __expf(-gp));
            float rv = rep[(m0 + m) * 300 + n];
            float av = attn[(m0 + m) * 300 + n];
            float res = (gate * rv + (1.0f - gate) * av) * (float)mask[m0 + m];
            if (isbf) ((__hip_bfloat16*)outv)[(m0 + m) * 300 + n] = __float2bfloat16(res);
            else      ((float*)outv)[(m0 + m) * 300 + n] = res;
        }
    }
}

extern "C" void kernel_launch(void* const* d_in, const int* in_sizes, int n_in,
                              void* d_out, int out_size, void* d_ws, size_t ws_size,
                              hipStream_t stream) {
    const void* X   = d_in[0];
    const int*  msk = (const int*)d_in[1];
    const void* Wfc = d_in[2];
    const void* bfc = d_in[3];
    const void* W1  = d_in[4];
    const void* W2  = d_in[5];
    const void* b1  = d_in[6];
    const void* Wf1 = d_in[7];
    const void* Wf2 = d_in[8];
    const void* bfv = d_in[9];
    float* ws = (float*)d_ws;

    hipLaunchKernelGGL(k_prep, dim3(501), dim3(256), 0, stream,
                       Wfc, W1, W2, Wf1, Wf2, bfc, b1, bfv, ws);
    hipLaunchKernelGGL(k_mm1,  dim3(320), dim3(256), 0, stream,
                       X, Wfc, ws, ws + OFF_REP);
    hipLaunchKernelGGL(k_mm2,  dim3(640), dim3(256), 0, stream, ws, ws);
    hipLaunchKernelGGL(k_attn, dim3(512), dim3(320), 0, stream,
                       ws, msk, ws + OFF_ATTN);
    hipLaunchKernelGGL(k_mm3,  dim3(320), dim3(256), 0, stream,
                       ws, Wfc, msk, d_out);
}

// Round 8
// 150.496 us; speedup vs baseline: 1.5804x; 1.5804x over previous
//
#include <hip/hip_runtime.h>
#include <hip/hip_bf16.h>

#define Sx 256
#define Dx 300
#define Mx 1024
#define CC 5.0f

// float-offsets into ws
#define OFF_REP    0
#define OFF_DEP    307200
#define OFF_HEAD   614400
#define OFF_ATTN   921600
#define OFF_USHORT 1228800      // ushort arrays base (byte 4915200)
#define OFF_BIAS   1740800      // fp32: bfc@+0 (320), b1@+320, bf@+640
// ushort offsets from U = (ushort*)(ws + OFF_USHORT)
#define UWFCH 0                 // [320n][320k]
#define UWFCL 102400
#define UW12H 204800            // [640n][320k]  n<300:W1, 320..619:W2
#define UW12L 409600
#define UWF12H 614400           // [320n][640k]  k<300:Wf1, 320..619:Wf2
#define UWF12L 819200

typedef __attribute__((ext_vector_type(8))) short short8;
typedef __attribute__((ext_vector_type(4))) float f32x4;

__device__ __forceinline__ float bf2f(unsigned short u) {
    union { unsigned int i; float f; } v; v.i = ((unsigned int)u) << 16; return v.f;
}
__device__ __forceinline__ unsigned short f2bf(float x) {   // RNE
    union { float f; unsigned int i; } u; u.f = x;
    unsigned int r = u.i + 0x7FFFu + ((u.i >> 16) & 1u);
    return (unsigned short)(r >> 16);
}
__device__ __forceinline__ int detect_bf16(const void* w) {
    const unsigned short* u = (const unsigned short*)w;
    int ok = 1;
    #pragma unroll
    for (int t = 0; t < 64; ++t) { float v = bf2f(u[t]); ok &= (fabsf(v) < 1.0f) ? 1 : 0; }
    return ok;
}
__device__ __forceinline__ float ldf(const void* p, int idx, int isbf) {
    return isbf ? bf2f(((const unsigned short*)p)[idx]) : ((const float*)p)[idx];
}

// ---------------------------------------------------------------------------
// k_prep: split+pad the 5 weight matrices into hi/lo bf16 [n][k] arrays + biases.
// one element per thread; grid 2004 x 256.
// ---------------------------------------------------------------------------
__global__ __launch_bounds__(256) void k_prep(
        const void* __restrict__ Wfc, const void* __restrict__ W1,
        const void* __restrict__ W2,  const void* __restrict__ Wf1,
        const void* __restrict__ Wf2, const void* __restrict__ bfc,
        const void* __restrict__ b1,  const void* __restrict__ bfv,
        float* __restrict__ ws) {
    __shared__ int s_isbf;
    if (threadIdx.x == 0) s_isbf = detect_bf16(Wfc);
    __syncthreads();
    const int isbf = s_isbf;
    const unsigned int idx = blockIdx.x * 256 + threadIdx.x;
    if (idx >= 512960u) return;
    unsigned short* U = (unsigned short*)(ws + OFF_USHORT);
    if (idx < 512000u) {
        int hOff, lOff, pos; float val = 0.f;
        if (idx < 102400u) {
            pos = idx; hOff = UWFCH; lOff = UWFCL;
            int n = idx / 320, k = idx % 320;
            if (n < 300 && k < 300) val = ldf(Wfc, n * 300 + k, isbf);
        } else if (idx < 307200u) {
            int j = idx - 102400; pos = j; hOff = UW12H; lOff = UW12L;
            int n = j / 320, k = j % 320;
            if (k < 300) {
                if (n < 300) val = ldf(W1, n * 300 + k, isbf);
                else if (n >= 320 && n < 620) val = ldf(W2, (n - 320) * 300 + k, isbf);
            }
        } else {
            int j = idx - 307200; pos = j; hOff = UWF12H; lOff = UWF12L;
            int n = j / 640, k = j % 640;
            if (n < 300) {
                if (k < 300) val = ldf(Wf1, n * 300 + k, isbf);
                else if (k >= 320 && k < 620) val = ldf(Wf2, n * 300 + (k - 320), isbf);
            }
        }
        unsigned short h = f2bf(val);
        unsigned short lo = f2bf(val - bf2f(h));
        U[hOff + pos] = h;
        U[lOff + pos] = lo;
    } else {
        int j = idx - 512000;
        int wb = j / 320, o = j % 320;
        const void* src = (wb == 0) ? bfc : (wb == 1 ? b1 : bfv);
        ws[OFF_BIAS + j] = (o < 300) ? ldf(src, o, isbf) : 0.0f;
    }
}

// ---------------------------------------------------------------------------
// MFMA GEMM kernels: tile M=32 x N=64, 256 thr (4 waves), K-chunks of 64.
// wave w: m-sub = w&1, n-subs {2*(w>>1), 2*(w>>1)+1}. hi/lo split: 3 MFMA.
// ---------------------------------------------------------------------------
#define MM_COMPUTE_CHUNK()                                                     \
    _Pragma("unroll")                                                          \
    for (int ks = 0; ks < 2; ++ks) {                                           \
        const int kb = ks * 32 + (l >> 4) * 8;                                 \
        short8 a_h = *(const short8*)&Ah[mo + (l & 15)][kb];                   \
        short8 a_l = *(const short8*)&Al[mo + (l & 15)][kb];                   \
        short8 b0h = *(const short8*)&Bh[nsb * 16 + (l & 15)][kb];             \
        short8 b0l = *(const short8*)&Bl[nsb * 16 + (l & 15)][kb];             \
        short8 b1h = *(const short8*)&Bh[(nsb + 1) * 16 + (l & 15)][kb];       \
        short8 b1l = *(const short8*)&Bl[(nsb + 1) * 16 + (l & 15)][kb];       \
        acc0 = __builtin_amdgcn_mfma_f32_16x16x32_bf16(a_h, b0h, acc0, 0, 0, 0); \
        acc0 = __builtin_amdgcn_mfma_f32_16x16x32_bf16(a_h, b0l, acc0, 0, 0, 0); \
        acc0 = __builtin_amdgcn_mfma_f32_16x16x32_bf16(a_l, b0h, acc0, 0, 0, 0); \
        acc1 = __builtin_amdgcn_mfma_f32_16x16x32_bf16(a_h, b1h, acc1, 0, 0, 0); \
        acc1 = __builtin_amdgcn_mfma_f32_16x16x32_bf16(a_h, b1l, acc1, 0, 0, 0); \
        acc1 = __builtin_amdgcn_mfma_f32_16x16x32_bf16(a_l, b1h, acc1, 0, 0, 0); \
    }

// k_mm1: rep = elu(X @ Wfc^T + bfc). grid 160 = 32mt x 5nt.
__global__ __launch_bounds__(256) void k_mm1(
        const void* __restrict__ Xv, const void* __restrict__ Wdet,
        float* __restrict__ ws) {
    __shared__ __align__(16) unsigned short Ah[32][72], Al[32][72];
    __shared__ __align__(16) unsigned short Bh[64][72], Bl[64][72];
    __shared__ int s_isbf;
    const int tid = threadIdx.x;
    if (tid == 0) s_isbf = detect_bf16(Wdet);
    __syncthreads();
    const int isbf = s_isbf;
    const int mt = blockIdx.x / 5, nt = blockIdx.x % 5;
    const int m0 = mt * 32, n0 = nt * 64;
    const unsigned short* WH = (const unsigned short*)(ws + OFF_USHORT) + UWFCH;
    const unsigned short* WL = (const unsigned short*)(ws + OFF_USHORT) + UWFCL;
    const int w = tid >> 6, l = tid & 63;
    const int mo = (w & 1) * 16, nsb = (w >> 1) * 2;
    const int ar = tid >> 3, ac = (tid & 7) * 8;
    const int bn = tid >> 2, bc = (tid & 3) * 16;
    f32x4 acc0 = {0.f, 0.f, 0.f, 0.f}, acc1 = {0.f, 0.f, 0.f, 0.f};
    for (int kc = 0; kc < 5; ++kc) {
        const int k0 = kc * 64;
        __syncthreads();
        {   // stage A
            union { unsigned short us[8]; short8 v; } ph, pl;
            const int m = m0 + ar;
            if (isbf) {
                const unsigned short* Xp = (const unsigned short*)Xv + m * 300;
                #pragma unroll
                for (int j = 0; j < 8; ++j) {
                    int k = k0 + ac + j;
                    ph.us[j] = (k < 300) ? Xp[k] : (unsigned short)0;
                    pl.us[j] = 0;
                }
            } else {
                const float* Xp = (const float*)Xv + m * 300;
                #pragma unroll
                for (int j = 0; j < 8; ++j) {
                    int k = k0 + ac + j;
                    float x = (k < 300) ? Xp[k] : 0.f;
                    unsigned short h = f2bf(x);
                    ph.us[j] = h; pl.us[j] = f2bf(x - bf2f(h));
                }
            }
            *(short8*)&Ah[ar][ac] = ph.v;
            *(short8*)&Al[ar][ac] = pl.v;
        }
        {   // stage B (row stride 320)
            const unsigned short* ph = WH + (n0 + bn) * 320 + k0 + bc;
            const unsigned short* pl = WL + (n0 + bn) * 320 + k0 + bc;
            *(short8*)&Bh[bn][bc]     = *(const short8*)(ph);
            *(short8*)&Bh[bn][bc + 8] = *(const short8*)(ph + 8);
            *(short8*)&Bl[bn][bc]     = *(const short8*)(pl);
            *(short8*)&Bl[bn][bc + 8] = *(const short8*)(pl + 8);
        }
        __syncthreads();
        MM_COMPUTE_CHUNK()
    }
    const float* bias = ws + OFF_BIAS;
    #pragma unroll
    for (int t = 0; t < 2; ++t) {
        f32x4 acc = t ? acc1 : acc0;
        const int n_g = n0 + (nsb + t) * 16 + (l & 15);
        if (n_g < 300) {
            float bb = bias[n_g];
            #pragma unroll
            for (int r = 0; r < 4; ++r) {
                int m_g = m0 + mo + (l >> 4) * 4 + r;
                float v = acc[r] + bb;
                v = v > 0.f ? v : (__expf(v) - 1.f);
                ws[OFF_REP + m_g * 300 + n_g] = v;
            }
        }
    }
}

// k_mm2: dep = rep@W1^T + b1 ; head = rep@W2^T. grid 320 = 32mt x 10nt.
__global__ __launch_bounds__(256) void k_mm2(float* __restrict__ ws) {
    __shared__ __align__(16) unsigned short Ah[32][72], Al[32][72];
    __shared__ __align__(16) unsigned short Bh[64][72], Bl[64][72];
    const int tid = threadIdx.x;
    const int mt = blockIdx.x / 10, nt = blockIdx.x % 10;
    const int m0 = mt * 32, n0 = nt * 64;
    const unsigned short* WH = (const unsigned short*)(ws + OFF_USHORT) + UW12H;
    const unsigned short* WL = (const unsigned short*)(ws + OFF_USHORT) + UW12L;
    const int w = tid >> 6, l = tid & 63;
    const int mo = (w & 1) * 16, nsb = (w >> 1) * 2;
    const int ar = tid >> 3, ac = (tid & 7) * 8;
    const int bn = tid >> 2, bc = (tid & 3) * 16;
    f32x4 acc0 = {0.f, 0.f, 0.f, 0.f}, acc1 = {0.f, 0.f, 0.f, 0.f};
    for (int kc = 0; kc < 5; ++kc) {
        const int k0 = kc * 64;
        __syncthreads();
        {
            union { unsigned short us[8]; short8 v; } ph, pl;
            const float* Xp = ws + OFF_REP + (m0 + ar) * 300;
            #pragma unroll
            for (int j = 0; j < 8; ++j) {
                int k = k0 + ac + j;
                float x = (k < 300) ? Xp[k] : 0.f;
                unsigned short h = f2bf(x);
                ph.us[j] = h; pl.us[j] = f2bf(x - bf2f(h));
            }
            *(short8*)&Ah[ar][ac] = ph.v;
            *(short8*)&Al[ar][ac] = pl.v;
        }
        {
            const unsigned short* ph = WH + (n0 + bn) * 320 + k0 + bc;
            const unsigned short* pl = WL + (n0 + bn) * 320 + k0 + bc;
            *(short8*)&Bh[bn][bc]     = *(const short8*)(ph);
            *(short8*)&Bh[bn][bc + 8] = *(const short8*)(ph + 8);
            *(short8*)&Bl[bn][bc]     = *(const short8*)(pl);
            *(short8*)&Bl[bn][bc + 8] = *(const short8*)(pl + 8);
        }
        __syncthreads();
        MM_COMPUTE_CHUNK()
    }
    const float* b1p = ws + OFF_BIAS + 320;
    #pragma unroll
    for (int t = 0; t < 2; ++t) {
        f32x4 acc = t ? acc1 : acc0;
        const int n_g = n0 + (nsb + t) * 16 + (l & 15);
        #pragma unroll
        for (int r = 0; r < 4; ++r) {
            int m_g = m0 + mo + (l >> 4) * 4 + r;
            if (n_g < 300)
                ws[OFF_DEP + m_g * 300 + n_g] = acc[r] + b1p[n_g];
            else if (n_g >= 320 && n_g < 620)
                ws[OFF_HEAD + m_g * 300 + (n_g - 320)] = acc[r];
        }
    }
}

// k_attn: single-pass branchless, fixed shift m=C (round-4 proven).
__global__ __launch_bounds__(320) void k_attn(
        const float* __restrict__ ws_ro, const int* __restrict__ mask,
        float* __restrict__ attn) {
    const float* dep  = ws_ro + OFF_DEP;
    const float* head = ws_ro + OFF_HEAD;
    const float* rep  = ws_ro + OFF_REP;
    __shared__ float mkf[256];
    const int blk = blockIdx.x;
    const int b = blk >> 7;
    const int tile = blk & 127;
    const int u = tile >> 1;
    const int i0 = (tile & 1) ? (254 - 2 * u) : (2 * u);
    const int tid = threadIdx.x;
    if (tid < 256) mkf[tid] = (float)mask[b * 256 + tid];
    __syncthreads();
    const int d = tid;
    if (d >= Dx) return;
    const int base = b * 256;

    const float hv0 = head[(base + i0) * Dx + d];
    const float hv1 = head[(base + i0 + 1) * Dx + d];
    const float pw0 = __expf(0.4f * hv0);
    const float pw1 = __expf(0.4f * hv1);

    float s0 = 0.f, r0 = 0.f, s1 = 0.f, r1 = 0.f;
    {
        const int j = i0 + 1;
        float dv = dep[(base + j) * Dx + d];
        float rv = rep[(base + j) * Dx + d];
        float mk = mkf[j];
        float ex = __expf(0.4f * dv);
        float u0 = fmaf(ex, pw0, 1.0f);
        float e0 = __expf(-10.0f * __builtin_amdgcn_rcpf(u0));
        float em0 = e0 * mk;
        s0 += em0; r0 = fmaf(em0, rv, r0);
    }
    const float* dp = dep + base * Dx + d;
    const float* rp = rep + base * Dx + d;
    #pragma unroll 4
    for (int j = i0 + 2; j < 256; ++j) {
        float dv = dp[j * Dx];
        float rv = rp[j * Dx];
        float mk = mkf[j];
        float ex = __expf(0.4f * dv);
        float u0 = fmaf(ex, pw0, 1.0f);
        float u1 = fmaf(ex, pw1, 1.0f);
        float e0 = __expf(-10.0f * __builtin_amdgcn_rcpf(u0));
        float e1 = __expf(-10.0f * __builtin_amdgcn_rcpf(u1));
        float em0 = e0 * mk;
        float em1 = e1 * mk;
        s0 += em0; r0 = fmaf(em0, rv, r0);
        s1 += em1; r1 = fmaf(em1, rv, r1);
    }
    const float den0 = s0 + (s0 == 0.f ? 1.f : 0.f) + 1e-20f;
    const float den1 = s1 + (s1 == 0.f ? 1.f : 0.f) + 1e-20f;
    attn[(base + i0) * Dx + d]     = r0 / den0;
    attn[(base + i0 + 1) * Dx + d] = r1 / den1;
}

// k_mm3: gate GEMM over [rep|attn] (Kpad=640), sigmoid blend, mask, store.
// grid 160 = 32mt x 5nt.
__global__ __launch_bounds__(256) void k_mm3(
        float* __restrict__ ws, const void* __restrict__ Wdet,
        const int* __restrict__ mask, void* __restrict__ outv) {
    __shared__ __align__(16) unsigned short Ah[32][72], Al[32][72];
    __shared__ __align__(16) unsigned short Bh[64][72], Bl[64][72];
    __shared__ int s_isbf;
    const int tid = threadIdx.x;
    if (tid == 0) s_isbf = detect_bf16(Wdet);
    __syncthreads();
    const int isbf = s_isbf;
    const int mt = blockIdx.x / 5, nt = blockIdx.x % 5;
    const int m0 = mt * 32, n0 = nt * 64;
    const unsigned short* WH = (const unsigned short*)(ws + OFF_USHORT) + UWF12H;
    const unsigned short* WL = (const unsigned short*)(ws + OFF_USHORT) + UWF12L;
    const int w = tid >> 6, l = tid & 63;
    const int mo = (w & 1) * 16, nsb = (w >> 1) * 2;
    const int ar = tid >> 3, ac = (tid & 7) * 8;
    const int bn = tid >> 2, bc = (tid & 3) * 16;
    f32x4 acc0 = {0.f, 0.f, 0.f, 0.f}, acc1 = {0.f, 0.f, 0.f, 0.f};
    for (int kc = 0; kc < 10; ++kc) {
        const int k0 = kc * 64;
        __syncthreads();
        {   // stage A from [rep | pad | attn | pad]
            union { unsigned short us[8]; short8 v; } ph, pl;
            const float* repp = ws + OFF_REP  + (m0 + ar) * 300;
            const float* attp = ws + OFF_ATTN + (m0 + ar) * 300;
            #pragma unroll
            for (int j = 0; j < 8; ++j) {
                int kk = k0 + ac + j;
                float x = 0.f;
                if (kk < 300) x = repp[kk];
                else if (kk >= 320 && kk < 620) x = attp[kk - 320];
                unsigned short h = f2bf(x);
                ph.us[j] = h; pl.us[j] = f2bf(x - bf2f(h));
            }
            *(short8*)&Ah[ar][ac] = ph.v;
            *(short8*)&Al[ar][ac] = pl.v;
        }
        {   // stage B (row stride 640)
            const unsigned short* ph = WH + (n0 + bn) * 640 + k0 + bc;
            const unsigned short* pl = WL + (n0 + bn) * 640 + k0 + bc;
            *(short8*)&Bh[bn][bc]     = *(const short8*)(ph);
            *(short8*)&Bh[bn][bc + 8] = *(const short8*)(ph + 8);
            *(short8*)&Bl[bn][bc]     = *(const short8*)(pl);
            *(short8*)&Bl[bn][bc + 8] = *(const short8*)(pl + 8);
        }
        __syncthreads();
        MM_COMPUTE_CHUNK()
    }
    const float* bfp = ws + OFF_BIAS + 640;
    #pragma unroll
    for (int t = 0; t < 2; ++t) {
        f32x4 acc = t ? acc1 : acc0;
        const int n_g = n0 + (nsb + t) * 16 + (l & 15);
        if (n_g < 300) {
            float bb = bfp[n_g];
            #pragma unroll
            for (int r = 0; r < 4; ++r) {
                int m_g = m0 + mo + (l >> 4) * 4 + r;
                float gp = acc[r] + bb;
                float gate = 1.0f / (1.0f + __expf(-gp));
                float rv = ws[OFF_REP  + m_g * 300 + n_g];
                float av = ws[OFF_ATTN + m_g * 300 + n_g];
                float res = (gate * rv + (1.0f - gate) * av) * (float)mask[m_g];
                if (isbf) ((__hip_bfloat16*)outv)[m_g * 300 + n_g] = __float2bfloat16(res);
                else      ((float*)outv)[m_g * 300 + n_g] = res;
            }
        }
    }
}

extern "C" void kernel_launch(void* const* d_in, const int* in_sizes, int n_in,
                              void* d_out, int out_size, void* d_ws, size_t ws_size,
                              hipStream_t stream) {
    const void* X   = d_in[0];
    const int*  msk = (const int*)d_in[1];
    const void* Wfc = d_in[2];
    const void* bfc = d_in[3];
    const void* W1  = d_in[4];
    const void* W2  = d_in[5];
    const void* b1  = d_in[6];
    const void* Wf1 = d_in[7];
    const void* Wf2 = d_in[8];
    const void* bfv = d_in[9];
    float* ws = (float*)d_ws;

    hipLaunchKernelGGL(k_prep, dim3(2004), dim3(256), 0, stream,
                       Wfc, W1, W2, Wf1, Wf2, bfc, b1, bfv, ws);
    hipLaunchKernelGGL(k_mm1,  dim3(160), dim3(256), 0, stream, X, Wfc, ws);
    hipLaunchKernelGGL(k_mm2,  dim3(320), dim3(256), 0, stream, ws);
    hipLaunchKernelGGL(k_attn, dim3(512), dim3(320), 0, stream,
                       ws, msk, ws + OFF_ATTN);
    hipLaunchKernelGGL(k_mm3,  dim3(160), dim3(256), 0, stream,
                       ws, Wfc, msk, d_out);
}